// Round 14
// baseline (339.190 us; speedup 1.0000x reference)
//
#include <hip/hip_runtime.h>
#include <math.h>

#define H_IMG 224
#define W_IMG 224
#define HW (H_IMG * W_IMG)
#define EPSF 1e-8f
#define NV 6890
#define NF 13776
#define NB 2
#define FCHUNK 128
#define NCHUNK ((NF + FCHUNK - 1) / FCHUNK)   // 108
#define FPAD (NCHUNK * FCHUNK)                // 13824
#define NWAVE 8
#define NBUCK 1024
#define CHDR_STRIDE 128
#define KEY_INIT 0x7F800000FFFFFFFFULL        // zp=+inf, idx=~0

// workspace byte offsets (256-aligned)
#define OFF_ZBU   0u                          // NB*NF*4   = 110,208
#define OFF_ZBS   110336u                     // NB*FPAD*4 = 110,592
#define OFF_BBS   220928u                     // NB*FPAD*16= 442,368
#define OFF_GMS   663296u                     // NB*FPAD*64= 1,769,472
#define OFF_OIS   2432768u                    // NB*FPAD*4 = 110,592
#define OFF_INV   2543360u                    // NB*NF*4   = 110,208
#define OFF_CHDR  2653696u                    // NB*128*4  = 1,024
#define OFF_CNT   2654720u                    // NB*1024*4 = 8,192
#define OFF_OFFS  2662912u                    // NB*1024*4 = 8,192  (end ~2.67 MB)

__device__ inline unsigned long long shfl_xor_u64(unsigned long long v, int m) {
  unsigned lo = (unsigned)v, hi = (unsigned)(v >> 32);
  lo = __shfl_xor(lo, m);
  hi = __shfl_xor(hi, m);
  return ((unsigned long long)hi << 32) | lo;
}

struct Cam { float m[9]; float t0, t1, t2, fx, fy, cx, cy; };

__device__ inline Cam load_cam(const float* cf, const float* cc,
                               const float* ct, const float* crt) {
  Cam C;
  float r0 = crt[0], r1 = crt[1], r2 = crt[2];
  float ss = __fadd_rn(__fadd_rn(__fmul_rn(r0, r0), __fmul_rn(r1, r1)), __fmul_rn(r2, r2));
  float th = sqrtf(__fadd_rn(ss, 1e-12f));
  float kx = r0 / th, ky = r1 / th, kz = r2 / th;
  float c = cosf(th), s = sinf(th), oc = 1.0f - c;
  C.m[0] = c + oc * kx * kx;      C.m[1] = oc * kx * ky - s * kz; C.m[2] = oc * kx * kz + s * ky;
  C.m[3] = oc * ky * kx + s * kz; C.m[4] = c + oc * ky * ky;      C.m[5] = oc * ky * kz - s * kx;
  C.m[6] = oc * kz * kx - s * ky; C.m[7] = oc * kz * ky + s * kx; C.m[8] = c + oc * kz * kz;
  C.t0 = ct[0]; C.t1 = ct[1]; C.t2 = ct[2];
  C.fx = cf[0]; C.fy = cf[1]; C.cx = cc[0]; C.cy = cc[1];
  return C;
}

// (u, v, zc) for one vertex — same expressions in every caller; the zb slack
// (1e-3) absorbs any cross-kernel contraction-ulp differences.
__device__ inline float3 proj_one(const Cam& C, const float* vp) {
  float x = vp[0], y = vp[1], z = vp[2];
  float xc = C.m[0] * x + C.m[1] * y + C.m[2] * z + C.t0;
  float yc = C.m[3] * x + C.m[4] * y + C.m[5] * z + C.t1;
  float zc = C.m[6] * x + C.m[7] * y + C.m[8] * z + C.t2;
  float zs = fmaxf(zc, EPSF);
  float u = __fadd_rn(__fmul_rn(xc / zs, C.fx), C.cx);
  float w = __fadd_rn(__fmul_rn(yc / zs, C.fy), C.cy);
  return make_float3(u, w, zc);
}

// Fused: sentinel-init of sorted SoA pads + per-face depth lower bound +
// bucket histogram (cnt pre-zeroed by hipMemsetAsync).
// zb <= zp guaranteed: zp = 1/(sum b_i/z_i) >= minz/(1+serr), serr ~ 3*werr/|area|,
// werr ~5 ulps of the largest edge-function product term. Tight bound (slack
// 1e-3) only when 3*werr <= 5e-4*|area|; else zb=0 (never depth-culled).
__global__ void zb_init_kernel(const float* __restrict__ v, const int* __restrict__ f,
                               const float* __restrict__ cf, const float* __restrict__ cc,
                               const float* __restrict__ ct, const float* __restrict__ crt,
                               float* __restrict__ zbU, unsigned* __restrict__ cnt,
                               float* __restrict__ zbS, float4* __restrict__ bbS) {
  int i = blockIdx.x * blockDim.x + threadIdx.x;
  if (i < NB * FPAD) {
    zbS[i] = 3e30f;                                      // pad: sorts last
    bbS[i] = make_float4(1e30f, -1e30f, 1e30f, -1e30f);  // always-miss bbox
  }
  if (i >= NB * NF) return;
  int b = i / NF, fi = i - b * NF;
  Cam C = load_cam(cf, cc, ct, crt);
  int i0 = f[fi * 3 + 0], i1 = f[fi * 3 + 1], i2 = f[fi * 3 + 2];
  float3 p0 = proj_one(C, v + ((size_t)b * NV + i0) * 3);
  float3 p1 = proj_one(C, v + ((size_t)b * NV + i1) * 3);
  float3 p2 = proj_one(C, v + ((size_t)b * NV + i2) * 3);
  float area = __fsub_rn(__fmul_rn(__fsub_rn(p1.x, p0.x), __fsub_rn(p2.y, p0.y)),
                         __fmul_rn(__fsub_rn(p1.y, p0.y), __fsub_rn(p2.x, p0.x)));
  bool nz = fabsf(area) > EPSF;
  bool zv = (p0.z > EPSF) && (p1.z > EPSF) && (p2.z > EPSF);
  bool ok = nz && zv;
  float zb;
  if (!ok) {
    zb = 3e30f;  // invalid: can never hit (inv_z <= EPS); sorts last
  } else {
    float minz = fminf(fminf(fmaxf(p0.z, EPSF), fmaxf(p1.z, EPSF)), fmaxf(p2.z, EPSF));
    float M = fmaxf(fmaxf(fmaxf(fabsf(p0.x), fabsf(p0.y)), fmaxf(fabsf(p1.x), fabsf(p1.y))),
                    fmaxf(fabsf(p2.x), fabsf(p2.y)));
    float werr = (2.0f * M) * (M + 256.0f) * 6e-7f;
    bool tight = (3.0f * werr) <= (5e-4f * fabsf(area));
    zb = tight ? __fmul_rn(minz, 0.999f) : 0.0f;
  }
  zbU[i] = zb;
  int bucket = (int)fminf(fmaxf(zb * 256.0f, 0.0f), (float)(NBUCK - 1));
  atomicAdd(&cnt[b * NBUCK + bucket], 1u);
}

// Shfl scan over 1024 buckets + chdr derivation. chdr[c] = (first bucket
// whose inclusive end exceeds c*FCHUNK)/256 — a lower bound on zb of EVERY
// face at positions >= c*FCHUNK (face in bucket b' has zb >= b'/256), and
// monotone in c => suffix-min property for free. Exact float: b'/256, b'<1024.
__global__ __launch_bounds__(1024) void scan_kernel(const unsigned* __restrict__ cnt,
                                                    unsigned* __restrict__ offs,
                                                    unsigned* __restrict__ chdr) {
  __shared__ unsigned wsum[16];
  __shared__ unsigned ends[NBUCK];
  int t = threadIdx.x, b = blockIdx.x;
  int lane = t & 63, wid = t >> 6;
  unsigned v = cnt[b * NBUCK + t];
  unsigned acc = v;
  #pragma unroll
  for (int d = 1; d < 64; d <<= 1) {
    unsigned n = __shfl_up(acc, d);
    if (lane >= d) acc += n;
  }
  if (lane == 63) wsum[wid] = acc;
  __syncthreads();
  if (t < 16) {
    unsigned wv = wsum[t];
    #pragma unroll
    for (int d = 1; d < 16; d <<= 1) {
      unsigned n = __shfl_up(wv, d, 16);
      if (t >= d) wv += n;
    }
    wsum[t] = wv;
  }
  __syncthreads();
  unsigned base = (wid > 0) ? wsum[wid - 1] : 0u;
  unsigned incl = base + acc;
  offs[b * NBUCK + t] = incl - v;  // exclusive
  ends[t] = incl;                  // inclusive
  __syncthreads();
  if (t < NCHUNK) {
    unsigned pos0 = (unsigned)(t * FCHUNK);
    int lo = 0, hi = NBUCK - 1;
    while (lo < hi) {
      int mid = (lo + hi) >> 1;
      if (ends[mid] > pos0) hi = mid; else lo = mid + 1;
    }
    chdr[b * CHDR_STRIDE + t] = __float_as_uint((float)lo * (1.0f / 256.0f));
  }
}

// Scatter into depth-sorted SoA (projections recomputed; record values use the
// exact reference fp32 op sequence -> bit-identical regardless of bucket pos).
__global__ void scatter_kernel(const float* __restrict__ v, const int* __restrict__ f,
                               const float* __restrict__ cf, const float* __restrict__ cc,
                               const float* __restrict__ ct, const float* __restrict__ crt,
                               const float* __restrict__ zbU, unsigned* __restrict__ offs,
                               float* __restrict__ zbS, float4* __restrict__ bbS,
                               float4* __restrict__ gmS, int* __restrict__ oiS,
                               int* __restrict__ inv) {
  int i = blockIdx.x * blockDim.x + threadIdx.x;
  if (i >= NB * NF) return;
  int b = i / NF, fi = i - b * NF;
  float zb = zbU[i];
  int bucket = (int)fminf(fmaxf(zb * 256.0f, 0.0f), (float)(NBUCK - 1));
  unsigned pos = atomicAdd(&offs[b * NBUCK + bucket], 1u);
  Cam C = load_cam(cf, cc, ct, crt);
  int i0 = f[fi * 3 + 0], i1 = f[fi * 3 + 1], i2 = f[fi * 3 + 2];
  float3 p0 = proj_one(C, v + ((size_t)b * NV + i0) * 3);
  float3 p1 = proj_one(C, v + ((size_t)b * NV + i1) * 3);
  float3 p2 = proj_one(C, v + ((size_t)b * NV + i2) * 3);
  float x0 = p0.x, y0 = p0.y, z0 = p0.z;
  float x1 = p1.x, y1 = p1.y, z1 = p1.z;
  float x2 = p2.x, y2 = p2.y, z2 = p2.z;
  float area = __fsub_rn(__fmul_rn(__fsub_rn(x1, x0), __fsub_rn(y2, y0)),
                         __fmul_rn(__fsub_rn(y1, y0), __fsub_rn(x2, x0)));
  bool nz = fabsf(area) > EPSF;
  float inv_area = nz ? (1.0f / area) : 0.0f;
  bool zv = (z0 > EPSF) && (z1 > EPSF) && (z2 > EPSF);
  bool ok = nz && zv;
  float zz0 = ok ? fmaxf(z0, EPSF) : 1e30f;
  float zz1 = ok ? fmaxf(z1, EPSF) : 1e30f;
  float zz2 = ok ? fmaxf(z2, EPSF) : 1e30f;
  size_t sp_ = (size_t)b * FPAD + pos;
  zbS[sp_] = zb;
  bbS[sp_] = make_float4(fminf(fminf(x0, x1), x2), fmaxf(fmaxf(x0, x1), x2),
                         fminf(fminf(y0, y1), y2), fmaxf(fmaxf(y0, y1), y2));
  gmS[sp_ * 4 + 0] = make_float4(__fsub_rn(x2, x1), __fsub_rn(y2, y1), x1, y1);
  gmS[sp_ * 4 + 1] = make_float4(__fsub_rn(x0, x2), __fsub_rn(y0, y2), x2, y2);
  gmS[sp_ * 4 + 2] = make_float4(__fsub_rn(x1, x0), __fsub_rn(y1, y0), x0, y0);
  gmS[sp_ * 4 + 3] = make_float4(zz0, zz1, zz2, inv_area);
  oiS[sp_] = fi;
  inv[i] = (int)pos;
}

// Block = 8 waves (512 thr), ALL on the same 4x4 pixel tile; chunk split 8-way
// interleaved. Cross-wave bound sharing via LDS u32 hints (CU-coherent; u32
// writes can't tear). Exact winner in registers: per-lane 64-bit packed key,
// slot-merged via shfl, published post-loop, min-reduced after __syncthreads.
// One block per tile -> no global atomics; shade fused into the epilogue.
// Skips strictly conservative; winner = exact min of (zp_bits<<32)|orig_idx.
__global__ __launch_bounds__(512) void raster_kernel(
    const unsigned* __restrict__ chdr,
    const float* __restrict__ zbS,
    const float4* __restrict__ bbS,
    const float4* __restrict__ gmS,
    const int* __restrict__ oiS,
    const int* __restrict__ inv,
    const int* __restrict__ f,
    const float* __restrict__ vc,
    const float* __restrict__ bg,
    float* __restrict__ out) {
  __shared__ unsigned hint[NWAVE][16];            // [wave][pixel] zp bits
  __shared__ unsigned long long fin[NWAVE][16];   // [wave][pixel] final keys
  int b = blockIdx.z;
  int w = threadIdx.x >> 6;                       // 0..7
  int lane = threadIdx.x & 63;
  int slot = lane & 3;
  int p = lane >> 2;                              // 0..15
  int wx = blockIdx.x * 4, wy = blockIdx.y * 4;
  int x = wx + (p & 3), y = wy + (p >> 2);
  float px = (float)x + 0.5f, py = (float)y + 0.5f;
  float tx0 = (float)wx + 0.5f, tx1 = (float)wx + 3.5f;
  float ty0 = (float)wy + 0.5f, ty1 = (float)wy + 3.5f;
  const unsigned* chdrB = chdr + b * CHDR_STRIDE;
  const float*  zbB = zbS + (size_t)b * FPAD;
  const float4* bbB = bbS + (size_t)b * FPAD;
  const float4* gmB = gmS + (size_t)b * FPAD * 4;
  const int*    oiB = oiS + (size_t)b * FPAD;

  if (threadIdx.x < NWAVE * 16) hint[threadIdx.x >> 4][threadIdx.x & 15] = 0x7F800000u;
  __syncthreads();

  unsigned long long bestKey = KEY_INIT;

  for (int c = w; c < NCHUNK; c += NWAVE) {
    // publish own per-pixel zp (slot-merged, single writer per [w][p])
    unsigned z_ = (unsigned)(bestKey >> 32);
    unsigned zo = __shfl_xor(z_, 1); if (zo < z_) z_ = zo;
    zo = __shfl_xor(z_, 2); if (zo < z_) z_ = zo;
    if (slot == 0) hint[w][p] = z_;
    // read all waves' hints (CU-coherent; stale = conservative)
    unsigned bzp = hint[0][p];
    #pragma unroll
    for (int hw_ = 1; hw_ < NWAVE; ++hw_) {
      unsigned hh = hint[hw_][p]; if (hh < bzp) bzp = hh;
    }
    float comb = __uint_as_float(bzp);                // pixel bound (all slots same)
    float czb = __uint_as_float(chdrB[c]);            // monotone lower bound, chunks >= c
    if (!__any(czb <= comb)) break;
    float combMax = fmaxf(comb, __shfl_xor(comb, 4)); // max over 16 pixels
    combMax = fmaxf(combMax, __shfl_xor(combMax, 8));
    combMax = fmaxf(combMax, __shfl_xor(combMax, 16));
    combMax = fmaxf(combMax, __shfl_xor(combMax, 32));
    int base = c * FCHUNK;
    #pragma unroll
    for (int h = 0; h < FCHUNK / 64; ++h) {
      int fbase = base + h * 64;
      float zb_lane = zbB[fbase + lane];              // coalesced, 1 per 64 faces
      float4 bb = bbB[fbase + lane];                  // coalesced bbox
      bool pass = (zb_lane <= combMax) &&
                  (bb.x <= tx1) && (bb.y >= tx0) &&   // bbox overlaps tile rect
                  (bb.z <= ty1) && (bb.w >= ty0);
      unsigned long long m = __ballot(pass);
      unsigned long long mm = m;
      while (mm) {
        int bit = __builtin_ctzll(mm);
        int g = bit & ~3;                             // nibble = 4-face group
        mm &= ~(0xFULL << g);
        if ((m >> (g + slot)) & 1) {
          int fi = fbase + g + slot;
          const float4* gm = &gmB[(size_t)fi * 4];
          float4 q0 = gm[0], q1 = gm[1], q2 = gm[2], q3 = gm[3];
          float w0 = __fsub_rn(__fmul_rn(q0.x, __fsub_rn(py, q0.w)),
                               __fmul_rn(q0.y, __fsub_rn(px, q0.z)));
          float w1 = __fsub_rn(__fmul_rn(q1.x, __fsub_rn(py, q1.w)),
                               __fmul_rn(q1.y, __fsub_rn(px, q1.z)));
          float w2 = __fsub_rn(__fmul_rn(q2.x, __fsub_rn(py, q2.w)),
                               __fmul_rn(q2.y, __fsub_rn(px, q2.z)));
          float b0 = __fmul_rn(w0, q3.w);
          float b1 = __fmul_rn(w1, q3.w);
          float b2 = __fmul_rn(w2, q3.w);
          if (b0 >= 0.0f && b1 >= 0.0f && b2 >= 0.0f) {
            float invz = __fadd_rn(__fadd_rn(b0 / q3.x, b1 / q3.y), b2 / q3.z);
            if (invz > EPSF) {
              float zp = 1.0f / invz;
              unsigned long long key =
                  ((unsigned long long)__float_as_uint(zp) << 32) | (unsigned)oiB[fi];
              if (key < bestKey) bestKey = key;
            }
          }
        }
      }
    }
  }

  // exact per-wave per-pixel merge (slots), publish, then block-wide merge
  unsigned long long o = shfl_xor_u64(bestKey, 1);
  if (o < bestKey) bestKey = o;
  o = shfl_xor_u64(bestKey, 2);
  if (o < bestKey) bestKey = o;
  if (slot == 0) fin[w][p] = bestKey;
  __syncthreads();

  int t = threadIdx.x;
  if (t < 16) {
    unsigned long long key = fin[0][t];
    #pragma unroll
    for (int hw_ = 1; hw_ < NWAVE; ++hw_) {
      unsigned long long kk = fin[hw_][t]; if (kk < key) key = kk;
    }
    int xx = wx + (t & 3), yy = wy + (t >> 2);
    float pxx = (float)xx + 0.5f, pyy = (float)yy + 0.5f;
    float o0, o1, o2;
    if (key != KEY_INIT) {
      int best = (int)(unsigned)(key & 0xFFFFFFFFu);
      float zmin = __uint_as_float((unsigned)(key >> 32));
      int pos = inv[b * NF + best];
      const float4* g = &gmB[(size_t)pos * 4];
      float4 q0 = g[0], q1 = g[1], q2 = g[2], q3 = g[3];
      float w0 = __fsub_rn(__fmul_rn(q0.x, __fsub_rn(pyy, q0.w)),
                           __fmul_rn(q0.y, __fsub_rn(pxx, q0.z)));
      float w1 = __fsub_rn(__fmul_rn(q1.x, __fsub_rn(pyy, q1.w)),
                           __fmul_rn(q1.y, __fsub_rn(pxx, q1.z)));
      float w2 = __fsub_rn(__fmul_rn(q2.x, __fsub_rn(pyy, q2.w)),
                           __fmul_rn(q2.y, __fsub_rn(pxx, q2.z)));
      float b0 = __fmul_rn(w0, q3.w), b1 = __fmul_rn(w1, q3.w), b2 = __fmul_rn(w2, q3.w);
      float pc0 = b0 / q3.x, pc1 = b1 / q3.y, pc2 = b2 / q3.z;
      int i0 = f[best * 3 + 0], i1 = f[best * 3 + 1], i2 = f[best * 3 + 2];
      const float* c0p = vc + (size_t)i0 * 3;
      const float* c1p = vc + (size_t)i1 * 3;
      const float* c2p = vc + (size_t)i2 * 3;
      o0 = __fmul_rn(__fadd_rn(__fadd_rn(__fmul_rn(pc0, c0p[0]), __fmul_rn(pc1, c1p[0])),
                               __fmul_rn(pc2, c2p[0])), zmin);
      o1 = __fmul_rn(__fadd_rn(__fadd_rn(__fmul_rn(pc0, c0p[1]), __fmul_rn(pc1, c1p[1])),
                               __fmul_rn(pc2, c2p[1])), zmin);
      o2 = __fmul_rn(__fadd_rn(__fadd_rn(__fmul_rn(pc0, c0p[2]), __fmul_rn(pc1, c1p[2])),
                               __fmul_rn(pc2, c2p[2])), zmin);
    } else {
      o0 = bg[0]; o1 = bg[1]; o2 = bg[2];
    }
    size_t oo = ((size_t)(b * H_IMG + yy) * W_IMG + xx) * 3;
    out[oo + 0] = o0;
    out[oo + 1] = o1;
    out[oo + 2] = o2;
  }
}

extern "C" void kernel_launch(void* const* d_in, const int* in_sizes, int n_in,
                              void* d_out, int out_size, void* d_ws, size_t ws_size,
                              hipStream_t stream) {
  const float* v   = (const float*)d_in[0];
  const float* vc  = (const float*)d_in[1];
  const float* bg  = (const float*)d_in[2];
  const float* cf  = (const float*)d_in[3];
  const float* cc  = (const float*)d_in[4];
  const float* ct  = (const float*)d_in[5];
  const float* crt = (const float*)d_in[6];
  const int*   f   = (const int*)d_in[7];
  float* out = (float*)d_out;
  char* ws = (char*)d_ws;

  float*    zbU   = (float*)(ws + OFF_ZBU);
  float*    zbS   = (float*)(ws + OFF_ZBS);
  float4*   bbS   = (float4*)(ws + OFF_BBS);
  float4*   gmS   = (float4*)(ws + OFF_GMS);
  int*      oiS   = (int*)(ws + OFF_OIS);
  int*      inv   = (int*)(ws + OFF_INV);
  unsigned* chdr  = (unsigned*)(ws + OFF_CHDR);
  unsigned* cnt   = (unsigned*)(ws + OFF_CNT);
  unsigned* offs  = (unsigned*)(ws + OFF_OFFS);

  hipMemsetAsync(cnt, 0, (size_t)NB * NBUCK * 4, stream);
  hipLaunchKernelGGL(zb_init_kernel, dim3((NB * FPAD + 255) / 256), dim3(256), 0, stream,
                     v, f, cf, cc, ct, crt, zbU, cnt, zbS, bbS);
  hipLaunchKernelGGL(scan_kernel, dim3(NB), dim3(1024), 0, stream, cnt, offs, chdr);
  hipLaunchKernelGGL(scatter_kernel, dim3((NB * NF + 255) / 256), dim3(256), 0, stream,
                     v, f, cf, cc, ct, crt, zbU, offs, zbS, bbS, gmS, oiS, inv);
  hipLaunchKernelGGL(raster_kernel, dim3(W_IMG / 4, H_IMG / 4, NB),
                     dim3(512), 0, stream,
                     chdr, zbS, bbS, gmS, oiS, inv, f, vc, bg, out);
}

// Round 15
// 335.566 us; speedup vs baseline: 1.0108x; 1.0108x over previous
//
#include <hip/hip_runtime.h>
#include <hip/hip_cooperative_groups.h>
#include <math.h>

namespace cg = cooperative_groups;

#define H_IMG 224
#define W_IMG 224
#define HW (H_IMG * W_IMG)
#define EPSF 1e-8f
#define NV 6890
#define NF 13776
#define NB 2
#define FCHUNK 128
#define NCHUNK ((NF + FCHUNK - 1) / FCHUNK)   // 108
#define FPAD (NCHUNK * FCHUNK)                // 13824
#define NWAVE 4
#define NBUCK 1024
#define CHDR_STRIDE 128
#define KEY_INIT 0x7F800000FFFFFFFFULL        // zp=+inf, idx=~0

// workspace byte offsets (256-aligned)
#define OFF_ZBU   0u                          // NB*NF*4   = 110,208
#define OFF_ZBS   110336u                     // NB*FPAD*4 = 110,592
#define OFF_BBS   220928u                     // NB*FPAD*16= 442,368
#define OFF_GMS   663296u                     // NB*FPAD*64= 1,769,472
#define OFF_OIS   2432768u                    // NB*FPAD*4 = 110,592
#define OFF_INV   2543360u                    // NB*NF*4   = 110,208
#define OFF_CHDR  2653696u                    // NB*128*4  = 1,024
#define OFF_CNT   2654720u                    // NB*1024*4 = 8,192
#define OFF_OFFS  2662912u                    // NB*1024*4 = 8,192  (end ~2.67 MB)

__device__ inline unsigned long long shfl_xor_u64(unsigned long long v, int m) {
  unsigned lo = (unsigned)v, hi = (unsigned)(v >> 32);
  lo = __shfl_xor(lo, m);
  hi = __shfl_xor(hi, m);
  return ((unsigned long long)hi << 32) | lo;
}

struct Cam { float m[9]; float t0, t1, t2, fx, fy, cx, cy; };

__device__ inline Cam load_cam(const float* cf, const float* cc,
                               const float* ct, const float* crt) {
  Cam C;
  float r0 = crt[0], r1 = crt[1], r2 = crt[2];
  float ss = __fadd_rn(__fadd_rn(__fmul_rn(r0, r0), __fmul_rn(r1, r1)), __fmul_rn(r2, r2));
  float th = sqrtf(__fadd_rn(ss, 1e-12f));
  float kx = r0 / th, ky = r1 / th, kz = r2 / th;
  float c = cosf(th), s = sinf(th), oc = 1.0f - c;
  C.m[0] = c + oc * kx * kx;      C.m[1] = oc * kx * ky - s * kz; C.m[2] = oc * kx * kz + s * ky;
  C.m[3] = oc * ky * kx + s * kz; C.m[4] = c + oc * ky * ky;      C.m[5] = oc * ky * kz - s * kx;
  C.m[6] = oc * kz * kx - s * ky; C.m[7] = oc * kz * ky + s * kx; C.m[8] = c + oc * kz * kz;
  C.t0 = ct[0]; C.t1 = ct[1]; C.t2 = ct[2];
  C.fx = cf[0]; C.fy = cf[1]; C.cx = cc[0]; C.cy = cc[1];
  return C;
}

// (u, v, zc) for one vertex — same expressions in every caller; the zb slack
// (1e-3) absorbs any cross-phase contraction-ulp differences.
__device__ inline float3 proj_one(const Cam& C, const float* vp) {
  float x = vp[0], y = vp[1], z = vp[2];
  float xc = C.m[0] * x + C.m[1] * y + C.m[2] * z + C.t0;
  float yc = C.m[3] * x + C.m[4] * y + C.m[5] * z + C.t1;
  float zc = C.m[6] * x + C.m[7] * y + C.m[8] * z + C.t2;
  float zs = fmaxf(zc, EPSF);
  float u = __fadd_rn(__fmul_rn(xc / zs, C.fx), C.cx);
  float w = __fadd_rn(__fmul_rn(yc / zs, C.fy), C.cy);
  return make_float3(u, w, zc);
}

// One cooperative launch replaces memset + zb_init + scan + scatter.
// Phase A: zero cnt, sentinel-init sorted-SoA pads.
// Phase B: per-face depth lower bound (zb <= zp guaranteed: zp >= minz/(1+serr),
//   serr ~ 3*werr/|area|, werr ~5 ulps of the largest edge product; tight bound
//   slack 1e-3 only when 3*werr <= 5e-4*|area|, else zb=0) + bucket histogram.
// Phase C (blocks 0..NB-1): segmented shfl scan over 1024 buckets + chdr[c] =
//   (first bucket whose inclusive end exceeds c*FCHUNK)/256 — lower bound on
//   zb of EVERY face at positions >= c*FCHUNK, monotone => suffix property.
// Phase D: scatter into depth-sorted SoA (exact reference fp32 op sequence ->
//   bit-identical records regardless of within-bucket position).
__global__ void prep_kernel(const float* __restrict__ v, const int* __restrict__ f,
                            const float* __restrict__ cf, const float* __restrict__ cc,
                            const float* __restrict__ ct, const float* __restrict__ crt,
                            float* __restrict__ zbU, unsigned* __restrict__ cnt,
                            unsigned* __restrict__ offs, unsigned* __restrict__ chdr,
                            float* __restrict__ zbS, float4* __restrict__ bbS,
                            float4* __restrict__ gmS, int* __restrict__ oiS,
                            int* __restrict__ inv) {
  cg::grid_group grid = cg::this_grid();
  int i = blockIdx.x * blockDim.x + threadIdx.x;

  // ---- Phase A ----
  if (i < NB * NBUCK) cnt[i] = 0u;
  if (i < NB * FPAD) {
    zbS[i] = 3e30f;                                      // pad: sorts last
    bbS[i] = make_float4(1e30f, -1e30f, 1e30f, -1e30f);  // always-miss bbox
  }
  grid.sync();

  // ---- Phase B ----
  if (i < NB * NF) {
    int b = i / NF, fi = i - b * NF;
    Cam C = load_cam(cf, cc, ct, crt);
    int i0 = f[fi * 3 + 0], i1 = f[fi * 3 + 1], i2 = f[fi * 3 + 2];
    float3 p0 = proj_one(C, v + ((size_t)b * NV + i0) * 3);
    float3 p1 = proj_one(C, v + ((size_t)b * NV + i1) * 3);
    float3 p2 = proj_one(C, v + ((size_t)b * NV + i2) * 3);
    float area = __fsub_rn(__fmul_rn(__fsub_rn(p1.x, p0.x), __fsub_rn(p2.y, p0.y)),
                           __fmul_rn(__fsub_rn(p1.y, p0.y), __fsub_rn(p2.x, p0.x)));
    bool nz = fabsf(area) > EPSF;
    bool zv = (p0.z > EPSF) && (p1.z > EPSF) && (p2.z > EPSF);
    bool ok = nz && zv;
    float zb;
    if (!ok) {
      zb = 3e30f;  // invalid: can never hit (inv_z <= EPS); sorts last
    } else {
      float minz = fminf(fminf(fmaxf(p0.z, EPSF), fmaxf(p1.z, EPSF)), fmaxf(p2.z, EPSF));
      float M = fmaxf(fmaxf(fmaxf(fabsf(p0.x), fabsf(p0.y)), fmaxf(fabsf(p1.x), fabsf(p1.y))),
                      fmaxf(fabsf(p2.x), fabsf(p2.y)));
      float werr = (2.0f * M) * (M + 256.0f) * 6e-7f;
      bool tight = (3.0f * werr) <= (5e-4f * fabsf(area));
      zb = tight ? __fmul_rn(minz, 0.999f) : 0.0f;
    }
    zbU[i] = zb;
    int bucket = (int)fminf(fmaxf(zb * 256.0f, 0.0f), (float)(NBUCK - 1));
    atomicAdd(&cnt[b * NBUCK + bucket], 1u);
  }
  grid.sync();

  // ---- Phase C ----
  __shared__ unsigned ends[NBUCK];
  __shared__ unsigned wsum[4];
  __shared__ unsigned carry_s;
  if (blockIdx.x < NB) {
    int b = blockIdx.x, t = threadIdx.x;
    int lane = t & 63, wid = t >> 6;
    if (t == 0) carry_s = 0u;
    for (int seg = 0; seg < NBUCK / 256; ++seg) {
      __syncthreads();                       // carry_s / wsum ready for reuse
      unsigned carry = carry_s;
      int idx = seg * 256 + t;
      unsigned vv = cnt[b * NBUCK + idx];
      unsigned acc = vv;
      #pragma unroll
      for (int d = 1; d < 64; d <<= 1) {
        unsigned n = __shfl_up(acc, d);
        if (lane >= d) acc += n;
      }
      if (lane == 63) wsum[wid] = acc;
      __syncthreads();
      unsigned wbase = 0;
      for (int k = 0; k < wid; ++k) wbase += wsum[k];
      unsigned incl = carry + wbase + acc;
      offs[b * NBUCK + idx] = incl - vv;     // exclusive
      ends[idx] = incl;                      // inclusive
      if (t == 255) carry_s = incl;
    }
    __syncthreads();
    if (t < NCHUNK) {
      unsigned pos0 = (unsigned)(t * FCHUNK);
      int lo = 0, hi = NBUCK - 1;
      while (lo < hi) {
        int mid = (lo + hi) >> 1;
        if (ends[mid] > pos0) hi = mid; else lo = mid + 1;
      }
      chdr[b * CHDR_STRIDE + t] = __float_as_uint((float)lo * (1.0f / 256.0f));
    }
  }
  grid.sync();

  // ---- Phase D ----
  if (i < NB * NF) {
    int b = i / NF, fi = i - b * NF;
    float zb = zbU[i];
    int bucket = (int)fminf(fmaxf(zb * 256.0f, 0.0f), (float)(NBUCK - 1));
    unsigned pos = atomicAdd(&offs[b * NBUCK + bucket], 1u);
    Cam C = load_cam(cf, cc, ct, crt);
    int i0 = f[fi * 3 + 0], i1 = f[fi * 3 + 1], i2 = f[fi * 3 + 2];
    float3 p0 = proj_one(C, v + ((size_t)b * NV + i0) * 3);
    float3 p1 = proj_one(C, v + ((size_t)b * NV + i1) * 3);
    float3 p2 = proj_one(C, v + ((size_t)b * NV + i2) * 3);
    float x0 = p0.x, y0 = p0.y, z0 = p0.z;
    float x1 = p1.x, y1 = p1.y, z1 = p1.z;
    float x2 = p2.x, y2 = p2.y, z2 = p2.z;
    float area = __fsub_rn(__fmul_rn(__fsub_rn(x1, x0), __fsub_rn(y2, y0)),
                           __fmul_rn(__fsub_rn(y1, y0), __fsub_rn(x2, x0)));
    bool nz = fabsf(area) > EPSF;
    float inv_area = nz ? (1.0f / area) : 0.0f;
    bool zv = (z0 > EPSF) && (z1 > EPSF) && (z2 > EPSF);
    bool ok = nz && zv;
    float zz0 = ok ? fmaxf(z0, EPSF) : 1e30f;
    float zz1 = ok ? fmaxf(z1, EPSF) : 1e30f;
    float zz2 = ok ? fmaxf(z2, EPSF) : 1e30f;
    size_t sp_ = (size_t)b * FPAD + pos;
    zbS[sp_] = zb;
    bbS[sp_] = make_float4(fminf(fminf(x0, x1), x2), fmaxf(fmaxf(x0, x1), x2),
                           fminf(fminf(y0, y1), y2), fmaxf(fmaxf(y0, y1), y2));
    gmS[sp_ * 4 + 0] = make_float4(__fsub_rn(x2, x1), __fsub_rn(y2, y1), x1, y1);
    gmS[sp_ * 4 + 1] = make_float4(__fsub_rn(x0, x2), __fsub_rn(y0, y2), x2, y2);
    gmS[sp_ * 4 + 2] = make_float4(__fsub_rn(x1, x0), __fsub_rn(y1, y0), x0, y0);
    gmS[sp_ * 4 + 3] = make_float4(zz0, zz1, zz2, inv_area);
    oiS[sp_] = fi;
    inv[i] = (int)pos;
  }
}

// Block = 4 waves (256 thr), ALL on the same 4x4 pixel tile; chunk split 4-way
// interleaved (R13's measured-optimal config; 8-wave duplicated the expensive
// loose-bound front chunks and regressed). Cross-wave bound sharing via LDS
// u32 hints (CU-coherent; u32 writes can't tear). Exact winner in registers:
// per-lane 64-bit packed key, slot-merged via shfl, published post-loop,
// min-reduced after __syncthreads. No global atomics; shade fused in epilogue.
// Skips strictly conservative; winner = exact min of (zp_bits<<32)|orig_idx.
__global__ __launch_bounds__(256) void raster_kernel(
    const unsigned* __restrict__ chdr,
    const float* __restrict__ zbS,
    const float4* __restrict__ bbS,
    const float4* __restrict__ gmS,
    const int* __restrict__ oiS,
    const int* __restrict__ inv,
    const int* __restrict__ f,
    const float* __restrict__ vc,
    const float* __restrict__ bg,
    float* __restrict__ out) {
  __shared__ unsigned hint[NWAVE][16];            // [wave][pixel] zp bits
  __shared__ unsigned long long fin[NWAVE][16];   // [wave][pixel] final keys
  int b = blockIdx.z;
  int w = threadIdx.x >> 6;                       // 0..3
  int lane = threadIdx.x & 63;
  int slot = lane & 3;
  int p = lane >> 2;                              // 0..15
  int wx = blockIdx.x * 4, wy = blockIdx.y * 4;
  int x = wx + (p & 3), y = wy + (p >> 2);
  float px = (float)x + 0.5f, py = (float)y + 0.5f;
  float tx0 = (float)wx + 0.5f, tx1 = (float)wx + 3.5f;
  float ty0 = (float)wy + 0.5f, ty1 = (float)wy + 3.5f;
  const unsigned* chdrB = chdr + b * CHDR_STRIDE;
  const float*  zbB = zbS + (size_t)b * FPAD;
  const float4* bbB = bbS + (size_t)b * FPAD;
  const float4* gmB = gmS + (size_t)b * FPAD * 4;
  const int*    oiB = oiS + (size_t)b * FPAD;

  if (threadIdx.x < NWAVE * 16) hint[threadIdx.x >> 4][threadIdx.x & 15] = 0x7F800000u;
  __syncthreads();

  unsigned long long bestKey = KEY_INIT;

  for (int c = w; c < NCHUNK; c += NWAVE) {
    // publish own per-pixel zp (slot-merged, single writer per [w][p])
    unsigned z_ = (unsigned)(bestKey >> 32);
    unsigned zo = __shfl_xor(z_, 1); if (zo < z_) z_ = zo;
    zo = __shfl_xor(z_, 2); if (zo < z_) z_ = zo;
    if (slot == 0) hint[w][p] = z_;
    // read all waves' hints (CU-coherent; stale = conservative)
    unsigned bzp = hint[0][p];
    #pragma unroll
    for (int hw_ = 1; hw_ < NWAVE; ++hw_) {
      unsigned hh = hint[hw_][p]; if (hh < bzp) bzp = hh;
    }
    float comb = __uint_as_float(bzp);                // pixel bound (all slots same)
    float czb = __uint_as_float(chdrB[c]);            // monotone lower bound, chunks >= c
    if (!__any(czb <= comb)) break;
    float combMax = fmaxf(comb, __shfl_xor(comb, 4)); // max over 16 pixels
    combMax = fmaxf(combMax, __shfl_xor(combMax, 8));
    combMax = fmaxf(combMax, __shfl_xor(combMax, 16));
    combMax = fmaxf(combMax, __shfl_xor(combMax, 32));
    int base = c * FCHUNK;
    #pragma unroll
    for (int h = 0; h < FCHUNK / 64; ++h) {
      int fbase = base + h * 64;
      float zb_lane = zbB[fbase + lane];              // coalesced, 1 per 64 faces
      float4 bb = bbB[fbase + lane];                  // coalesced bbox
      bool pass = (zb_lane <= combMax) &&
                  (bb.x <= tx1) && (bb.y >= tx0) &&   // bbox overlaps tile rect
                  (bb.z <= ty1) && (bb.w >= ty0);
      unsigned long long m = __ballot(pass);
      unsigned long long mm = m;
      while (mm) {
        int bit = __builtin_ctzll(mm);
        int g = bit & ~3;                             // nibble = 4-face group
        mm &= ~(0xFULL << g);
        if ((m >> (g + slot)) & 1) {
          int fi = fbase + g + slot;
          const float4* gm = &gmB[(size_t)fi * 4];
          float4 q0 = gm[0], q1 = gm[1], q2 = gm[2], q3 = gm[3];
          float w0 = __fsub_rn(__fmul_rn(q0.x, __fsub_rn(py, q0.w)),
                               __fmul_rn(q0.y, __fsub_rn(px, q0.z)));
          float w1 = __fsub_rn(__fmul_rn(q1.x, __fsub_rn(py, q1.w)),
                               __fmul_rn(q1.y, __fsub_rn(px, q1.z)));
          float w2 = __fsub_rn(__fmul_rn(q2.x, __fsub_rn(py, q2.w)),
                               __fmul_rn(q2.y, __fsub_rn(px, q2.z)));
          float b0 = __fmul_rn(w0, q3.w);
          float b1 = __fmul_rn(w1, q3.w);
          float b2 = __fmul_rn(w2, q3.w);
          if (b0 >= 0.0f && b1 >= 0.0f && b2 >= 0.0f) {
            float invz = __fadd_rn(__fadd_rn(b0 / q3.x, b1 / q3.y), b2 / q3.z);
            if (invz > EPSF) {
              float zp = 1.0f / invz;
              unsigned long long key =
                  ((unsigned long long)__float_as_uint(zp) << 32) | (unsigned)oiB[fi];
              if (key < bestKey) bestKey = key;
            }
          }
        }
      }
    }
  }

  // exact per-wave per-pixel merge (slots), publish, then block-wide merge
  unsigned long long o = shfl_xor_u64(bestKey, 1);
  if (o < bestKey) bestKey = o;
  o = shfl_xor_u64(bestKey, 2);
  if (o < bestKey) bestKey = o;
  if (slot == 0) fin[w][p] = bestKey;
  __syncthreads();

  int t = threadIdx.x;
  if (t < 16) {
    unsigned long long key = fin[0][t];
    #pragma unroll
    for (int hw_ = 1; hw_ < NWAVE; ++hw_) {
      unsigned long long kk = fin[hw_][t]; if (kk < key) key = kk;
    }
    int xx = wx + (t & 3), yy = wy + (t >> 2);
    float pxx = (float)xx + 0.5f, pyy = (float)yy + 0.5f;
    float o0, o1, o2;
    if (key != KEY_INIT) {
      int best = (int)(unsigned)(key & 0xFFFFFFFFu);
      float zmin = __uint_as_float((unsigned)(key >> 32));
      int pos = inv[b * NF + best];
      const float4* g = &gmB[(size_t)pos * 4];
      float4 q0 = g[0], q1 = g[1], q2 = g[2], q3 = g[3];
      float w0 = __fsub_rn(__fmul_rn(q0.x, __fsub_rn(pyy, q0.w)),
                           __fmul_rn(q0.y, __fsub_rn(pxx, q0.z)));
      float w1 = __fsub_rn(__fmul_rn(q1.x, __fsub_rn(pyy, q1.w)),
                           __fmul_rn(q1.y, __fsub_rn(pxx, q1.z)));
      float w2 = __fsub_rn(__fmul_rn(q2.x, __fsub_rn(pyy, q2.w)),
                           __fmul_rn(q2.y, __fsub_rn(pxx, q2.z)));
      float b0 = __fmul_rn(w0, q3.w), b1 = __fmul_rn(w1, q3.w), b2 = __fmul_rn(w2, q3.w);
      float pc0 = b0 / q3.x, pc1 = b1 / q3.y, pc2 = b2 / q3.z;
      int i0 = f[best * 3 + 0], i1 = f[best * 3 + 1], i2 = f[best * 3 + 2];
      const float* c0p = vc + (size_t)i0 * 3;
      const float* c1p = vc + (size_t)i1 * 3;
      const float* c2p = vc + (size_t)i2 * 3;
      o0 = __fmul_rn(__fadd_rn(__fadd_rn(__fmul_rn(pc0, c0p[0]), __fmul_rn(pc1, c1p[0])),
                               __fmul_rn(pc2, c2p[0])), zmin);
      o1 = __fmul_rn(__fadd_rn(__fadd_rn(__fmul_rn(pc0, c0p[1]), __fmul_rn(pc1, c1p[1])),
                               __fmul_rn(pc2, c2p[1])), zmin);
      o2 = __fmul_rn(__fadd_rn(__fadd_rn(__fmul_rn(pc0, c0p[2]), __fmul_rn(pc1, c1p[2])),
                               __fmul_rn(pc2, c2p[2])), zmin);
    } else {
      o0 = bg[0]; o1 = bg[1]; o2 = bg[2];
    }
    size_t oo = ((size_t)(b * H_IMG + yy) * W_IMG + xx) * 3;
    out[oo + 0] = o0;
    out[oo + 1] = o1;
    out[oo + 2] = o2;
  }
}

extern "C" void kernel_launch(void* const* d_in, const int* in_sizes, int n_in,
                              void* d_out, int out_size, void* d_ws, size_t ws_size,
                              hipStream_t stream) {
  const float* v   = (const float*)d_in[0];
  const float* vc  = (const float*)d_in[1];
  const float* bg  = (const float*)d_in[2];
  const float* cf  = (const float*)d_in[3];
  const float* cc  = (const float*)d_in[4];
  const float* ct  = (const float*)d_in[5];
  const float* crt = (const float*)d_in[6];
  const int*   f   = (const int*)d_in[7];
  float* out = (float*)d_out;
  char* ws = (char*)d_ws;

  float*    zbU   = (float*)(ws + OFF_ZBU);
  float*    zbS   = (float*)(ws + OFF_ZBS);
  float4*   bbS   = (float4*)(ws + OFF_BBS);
  float4*   gmS   = (float4*)(ws + OFF_GMS);
  int*      oiS   = (int*)(ws + OFF_OIS);
  int*      inv   = (int*)(ws + OFF_INV);
  unsigned* chdr  = (unsigned*)(ws + OFF_CHDR);
  unsigned* cnt   = (unsigned*)(ws + OFF_CNT);
  unsigned* offs  = (unsigned*)(ws + OFF_OFFS);

  void* args[] = { (void*)&v, (void*)&f, (void*)&cf, (void*)&cc, (void*)&ct,
                   (void*)&crt, (void*)&zbU, (void*)&cnt, (void*)&offs,
                   (void*)&chdr, (void*)&zbS, (void*)&bbS, (void*)&gmS,
                   (void*)&oiS, (void*)&inv };
  hipLaunchCooperativeKernel((void*)prep_kernel,
                             dim3((NB * FPAD + 255) / 256), dim3(256),
                             args, 0, stream);
  hipLaunchKernelGGL(raster_kernel, dim3(W_IMG / 4, H_IMG / 4, NB),
                     dim3(256), 0, stream,
                     chdr, zbS, bbS, gmS, oiS, inv, f, vc, bg, out);
}

// Round 16
// 287.327 us; speedup vs baseline: 1.1805x; 1.1679x over previous
//
#include <hip/hip_runtime.h>
#include <math.h>

#define H_IMG 224
#define W_IMG 224
#define HW (H_IMG * W_IMG)
#define EPSF 1e-8f
#define NV 6890
#define NF 13776
#define NB 2
#define FCHUNK 128
#define NCHUNK ((NF + FCHUNK - 1) / FCHUNK)   // 108
#define FPAD (NCHUNK * FCHUNK)                // 13824
#define NWAVE 4
#define NBUCK 1024
#define CHDR_STRIDE 128
#define KEY_INIT 0x7F800000FFFFFFFFULL        // zp=+inf, idx=~0

// workspace byte offsets (256-aligned)
#define OFF_ZBU   0u                          // NB*NF*4   = 110,208
#define OFF_ZBS   110336u                     // NB*FPAD*4 = 110,592
#define OFF_BBS   220928u                     // NB*FPAD*16= 442,368
#define OFF_GMS   663296u                     // NB*FPAD*64= 1,769,472
#define OFF_OIS   2432768u                    // NB*FPAD*4 = 110,592
#define OFF_INV   2543360u                    // NB*NF*4   = 110,208
#define OFF_CHDR  2653696u                    // NB*128*4  = 1,024
#define OFF_CNT   2654720u                    // NB*1024*4 = 8,192
#define OFF_OFFS  2662912u                    // NB*1024*4 = 8,192  (end ~2.67 MB)

__device__ inline unsigned long long shfl_xor_u64(unsigned long long v, int m) {
  unsigned lo = (unsigned)v, hi = (unsigned)(v >> 32);
  lo = __shfl_xor(lo, m);
  hi = __shfl_xor(hi, m);
  return ((unsigned long long)hi << 32) | lo;
}

struct Cam { float m[9]; float t0, t1, t2, fx, fy, cx, cy; };

__device__ inline Cam load_cam(const float* cf, const float* cc,
                               const float* ct, const float* crt) {
  Cam C;
  float r0 = crt[0], r1 = crt[1], r2 = crt[2];
  float ss = __fadd_rn(__fadd_rn(__fmul_rn(r0, r0), __fmul_rn(r1, r1)), __fmul_rn(r2, r2));
  float th = sqrtf(__fadd_rn(ss, 1e-12f));
  float kx = r0 / th, ky = r1 / th, kz = r2 / th;
  float c = cosf(th), s = sinf(th), oc = 1.0f - c;
  C.m[0] = c + oc * kx * kx;      C.m[1] = oc * kx * ky - s * kz; C.m[2] = oc * kx * kz + s * ky;
  C.m[3] = oc * ky * kx + s * kz; C.m[4] = c + oc * ky * ky;      C.m[5] = oc * ky * kz - s * kx;
  C.m[6] = oc * kz * kx - s * ky; C.m[7] = oc * kz * ky + s * kx; C.m[8] = c + oc * kz * kz;
  C.t0 = ct[0]; C.t1 = ct[1]; C.t2 = ct[2];
  C.fx = cf[0]; C.fy = cf[1]; C.cx = cc[0]; C.cy = cc[1];
  return C;
}

// (u, v, zc) for one vertex — same expressions in every caller; the zb slack
// (1e-3) absorbs any cross-kernel contraction-ulp differences.
__device__ inline float3 proj_one(const Cam& C, const float* vp) {
  float x = vp[0], y = vp[1], z = vp[2];
  float xc = C.m[0] * x + C.m[1] * y + C.m[2] * z + C.t0;
  float yc = C.m[3] * x + C.m[4] * y + C.m[5] * z + C.t1;
  float zc = C.m[6] * x + C.m[7] * y + C.m[8] * z + C.t2;
  float zs = fmaxf(zc, EPSF);
  float u = __fadd_rn(__fmul_rn(xc / zs, C.fx), C.cx);
  float w = __fadd_rn(__fmul_rn(yc / zs, C.fy), C.cy);
  return make_float3(u, w, zc);
}

// Fused: sentinel-init of sorted SoA pads + per-face depth lower bound +
// bucket histogram (cnt pre-zeroed by hipMemsetAsync).
// zb <= zp guaranteed: zp = 1/(sum b_i/z_i) >= minz/(1+serr), serr ~ 3*werr/|area|,
// werr ~5 ulps of the largest edge-function product term. Tight bound (slack
// 1e-3) only when 3*werr <= 5e-4*|area|; else zb=0 (never depth-culled).
__global__ void zb_init_kernel(const float* __restrict__ v, const int* __restrict__ f,
                               const float* __restrict__ cf, const float* __restrict__ cc,
                               const float* __restrict__ ct, const float* __restrict__ crt,
                               float* __restrict__ zbU, unsigned* __restrict__ cnt,
                               float* __restrict__ zbS, float4* __restrict__ bbS) {
  int i = blockIdx.x * blockDim.x + threadIdx.x;
  if (i < NB * FPAD) {
    zbS[i] = 3e30f;                                      // pad: sorts last
    bbS[i] = make_float4(1e30f, -1e30f, 1e30f, -1e30f);  // always-miss bbox
  }
  if (i >= NB * NF) return;
  int b = i / NF, fi = i - b * NF;
  Cam C = load_cam(cf, cc, ct, crt);
  int i0 = f[fi * 3 + 0], i1 = f[fi * 3 + 1], i2 = f[fi * 3 + 2];
  float3 p0 = proj_one(C, v + ((size_t)b * NV + i0) * 3);
  float3 p1 = proj_one(C, v + ((size_t)b * NV + i1) * 3);
  float3 p2 = proj_one(C, v + ((size_t)b * NV + i2) * 3);
  float area = __fsub_rn(__fmul_rn(__fsub_rn(p1.x, p0.x), __fsub_rn(p2.y, p0.y)),
                         __fmul_rn(__fsub_rn(p1.y, p0.y), __fsub_rn(p2.x, p0.x)));
  bool nz = fabsf(area) > EPSF;
  bool zv = (p0.z > EPSF) && (p1.z > EPSF) && (p2.z > EPSF);
  bool ok = nz && zv;
  float zb;
  if (!ok) {
    zb = 3e30f;  // invalid: can never hit (inv_z <= EPS); sorts last
  } else {
    float minz = fminf(fminf(fmaxf(p0.z, EPSF), fmaxf(p1.z, EPSF)), fmaxf(p2.z, EPSF));
    float M = fmaxf(fmaxf(fmaxf(fabsf(p0.x), fabsf(p0.y)), fmaxf(fabsf(p1.x), fabsf(p1.y))),
                    fmaxf(fabsf(p2.x), fabsf(p2.y)));
    float werr = (2.0f * M) * (M + 256.0f) * 6e-7f;
    bool tight = (3.0f * werr) <= (5e-4f * fabsf(area));
    zb = tight ? __fmul_rn(minz, 0.999f) : 0.0f;
  }
  zbU[i] = zb;
  int bucket = (int)fminf(fmaxf(zb * 256.0f, 0.0f), (float)(NBUCK - 1));
  atomicAdd(&cnt[b * NBUCK + bucket], 1u);
}

// Shfl scan over 1024 buckets + chdr derivation. chdr[c] = (first bucket
// whose inclusive end exceeds c*FCHUNK)/256 — a lower bound on zb of EVERY
// face at positions >= c*FCHUNK (face in bucket b' has zb >= b'/256), and
// monotone in c => suffix-min property for free. Exact float: b'/256, b'<1024.
__global__ __launch_bounds__(1024) void scan_kernel(const unsigned* __restrict__ cnt,
                                                    unsigned* __restrict__ offs,
                                                    unsigned* __restrict__ chdr) {
  __shared__ unsigned wsum[16];
  __shared__ unsigned ends[NBUCK];
  int t = threadIdx.x, b = blockIdx.x;
  int lane = t & 63, wid = t >> 6;
  unsigned v = cnt[b * NBUCK + t];
  unsigned acc = v;
  #pragma unroll
  for (int d = 1; d < 64; d <<= 1) {
    unsigned n = __shfl_up(acc, d);
    if (lane >= d) acc += n;
  }
  if (lane == 63) wsum[wid] = acc;
  __syncthreads();
  if (t < 16) {
    unsigned wv = wsum[t];
    #pragma unroll
    for (int d = 1; d < 16; d <<= 1) {
      unsigned n = __shfl_up(wv, d, 16);
      if (t >= d) wv += n;
    }
    wsum[t] = wv;
  }
  __syncthreads();
  unsigned base = (wid > 0) ? wsum[wid - 1] : 0u;
  unsigned incl = base + acc;
  offs[b * NBUCK + t] = incl - v;  // exclusive
  ends[t] = incl;                  // inclusive
  __syncthreads();
  if (t < NCHUNK) {
    unsigned pos0 = (unsigned)(t * FCHUNK);
    int lo = 0, hi = NBUCK - 1;
    while (lo < hi) {
      int mid = (lo + hi) >> 1;
      if (ends[mid] > pos0) hi = mid; else lo = mid + 1;
    }
    chdr[b * CHDR_STRIDE + t] = __float_as_uint((float)lo * (1.0f / 256.0f));
  }
}

// Scatter into depth-sorted SoA (projections recomputed; record values use the
// exact reference fp32 op sequence -> bit-identical regardless of bucket pos).
__global__ void scatter_kernel(const float* __restrict__ v, const int* __restrict__ f,
                               const float* __restrict__ cf, const float* __restrict__ cc,
                               const float* __restrict__ ct, const float* __restrict__ crt,
                               const float* __restrict__ zbU, unsigned* __restrict__ offs,
                               float* __restrict__ zbS, float4* __restrict__ bbS,
                               float4* __restrict__ gmS, int* __restrict__ oiS,
                               int* __restrict__ inv) {
  int i = blockIdx.x * blockDim.x + threadIdx.x;
  if (i >= NB * NF) return;
  int b = i / NF, fi = i - b * NF;
  float zb = zbU[i];
  int bucket = (int)fminf(fmaxf(zb * 256.0f, 0.0f), (float)(NBUCK - 1));
  unsigned pos = atomicAdd(&offs[b * NBUCK + bucket], 1u);
  Cam C = load_cam(cf, cc, ct, crt);
  int i0 = f[fi * 3 + 0], i1 = f[fi * 3 + 1], i2 = f[fi * 3 + 2];
  float3 p0 = proj_one(C, v + ((size_t)b * NV + i0) * 3);
  float3 p1 = proj_one(C, v + ((size_t)b * NV + i1) * 3);
  float3 p2 = proj_one(C, v + ((size_t)b * NV + i2) * 3);
  float x0 = p0.x, y0 = p0.y, z0 = p0.z;
  float x1 = p1.x, y1 = p1.y, z1 = p1.z;
  float x2 = p2.x, y2 = p2.y, z2 = p2.z;
  float area = __fsub_rn(__fmul_rn(__fsub_rn(x1, x0), __fsub_rn(y2, y0)),
                         __fmul_rn(__fsub_rn(y1, y0), __fsub_rn(x2, x0)));
  bool nz = fabsf(area) > EPSF;
  float inv_area = nz ? (1.0f / area) : 0.0f;
  bool zv = (z0 > EPSF) && (z1 > EPSF) && (z2 > EPSF);
  bool ok = nz && zv;
  float zz0 = ok ? fmaxf(z0, EPSF) : 1e30f;
  float zz1 = ok ? fmaxf(z1, EPSF) : 1e30f;
  float zz2 = ok ? fmaxf(z2, EPSF) : 1e30f;
  size_t sp_ = (size_t)b * FPAD + pos;
  zbS[sp_] = zb;
  bbS[sp_] = make_float4(fminf(fminf(x0, x1), x2), fmaxf(fmaxf(x0, x1), x2),
                         fminf(fminf(y0, y1), y2), fmaxf(fmaxf(y0, y1), y2));
  gmS[sp_ * 4 + 0] = make_float4(__fsub_rn(x2, x1), __fsub_rn(y2, y1), x1, y1);
  gmS[sp_ * 4 + 1] = make_float4(__fsub_rn(x0, x2), __fsub_rn(y0, y2), x2, y2);
  gmS[sp_ * 4 + 2] = make_float4(__fsub_rn(x1, x0), __fsub_rn(y1, y0), x0, y0);
  gmS[sp_ * 4 + 3] = make_float4(zz0, zz1, zz2, inv_area);
  oiS[sp_] = fi;
  inv[i] = (int)pos;
}

// Block = 4 waves (256 thr), ALL on the same 4x4 pixel tile; chunk split 4-way
// interleaved (R13's measured-optimal config; 8-wave duplicated the expensive
// loose-bound front chunks and regressed, R14). Cross-wave bound sharing via
// LDS u32 hints (CU-coherent; u32 writes can't tear). Exact winner in
// registers: per-lane 64-bit packed key, slot-merged via shfl, published
// post-loop, min-reduced after __syncthreads. No global atomics; shade fused
// in epilogue. Skips strictly conservative; winner = exact min of
// (zp_bits<<32)|orig_idx — reproduces jnp.argmin's lowest-index tie-break.
__global__ __launch_bounds__(256) void raster_kernel(
    const unsigned* __restrict__ chdr,
    const float* __restrict__ zbS,
    const float4* __restrict__ bbS,
    const float4* __restrict__ gmS,
    const int* __restrict__ oiS,
    const int* __restrict__ inv,
    const int* __restrict__ f,
    const float* __restrict__ vc,
    const float* __restrict__ bg,
    float* __restrict__ out) {
  __shared__ unsigned hint[NWAVE][16];            // [wave][pixel] zp bits
  __shared__ unsigned long long fin[NWAVE][16];   // [wave][pixel] final keys
  int b = blockIdx.z;
  int w = threadIdx.x >> 6;                       // 0..3
  int lane = threadIdx.x & 63;
  int slot = lane & 3;
  int p = lane >> 2;                              // 0..15
  int wx = blockIdx.x * 4, wy = blockIdx.y * 4;
  int x = wx + (p & 3), y = wy + (p >> 2);
  float px = (float)x + 0.5f, py = (float)y + 0.5f;
  float tx0 = (float)wx + 0.5f, tx1 = (float)wx + 3.5f;
  float ty0 = (float)wy + 0.5f, ty1 = (float)wy + 3.5f;
  const unsigned* chdrB = chdr + b * CHDR_STRIDE;
  const float*  zbB = zbS + (size_t)b * FPAD;
  const float4* bbB = bbS + (size_t)b * FPAD;
  const float4* gmB = gmS + (size_t)b * FPAD * 4;
  const int*    oiB = oiS + (size_t)b * FPAD;

  if (threadIdx.x < NWAVE * 16) hint[threadIdx.x >> 4][threadIdx.x & 15] = 0x7F800000u;
  __syncthreads();

  unsigned long long bestKey = KEY_INIT;

  for (int c = w; c < NCHUNK; c += NWAVE) {
    // publish own per-pixel zp (slot-merged, single writer per [w][p])
    unsigned z_ = (unsigned)(bestKey >> 32);
    unsigned zo = __shfl_xor(z_, 1); if (zo < z_) z_ = zo;
    zo = __shfl_xor(z_, 2); if (zo < z_) z_ = zo;
    if (slot == 0) hint[w][p] = z_;
    // read all waves' hints (CU-coherent; stale = conservative)
    unsigned bzp = hint[0][p];
    #pragma unroll
    for (int hw_ = 1; hw_ < NWAVE; ++hw_) {
      unsigned hh = hint[hw_][p]; if (hh < bzp) bzp = hh;
    }
    float comb = __uint_as_float(bzp);                // pixel bound (all slots same)
    float czb = __uint_as_float(chdrB[c]);            // monotone lower bound, chunks >= c
    if (!__any(czb <= comb)) break;
    float combMax = fmaxf(comb, __shfl_xor(comb, 4)); // max over 16 pixels
    combMax = fmaxf(combMax, __shfl_xor(combMax, 8));
    combMax = fmaxf(combMax, __shfl_xor(combMax, 16));
    combMax = fmaxf(combMax, __shfl_xor(combMax, 32));
    int base = c * FCHUNK;
    #pragma unroll
    for (int h = 0; h < FCHUNK / 64; ++h) {
      int fbase = base + h * 64;
      float zb_lane = zbB[fbase + lane];              // coalesced, 1 per 64 faces
      float4 bb = bbB[fbase + lane];                  // coalesced bbox
      bool pass = (zb_lane <= combMax) &&
                  (bb.x <= tx1) && (bb.y >= tx0) &&   // bbox overlaps tile rect
                  (bb.z <= ty1) && (bb.w >= ty0);
      unsigned long long m = __ballot(pass);
      unsigned long long mm = m;
      while (mm) {
        int bit = __builtin_ctzll(mm);
        int g = bit & ~3;                             // nibble = 4-face group
        mm &= ~(0xFULL << g);
        if ((m >> (g + slot)) & 1) {
          int fi = fbase + g + slot;
          const float4* gm = &gmB[(size_t)fi * 4];
          float4 q0 = gm[0], q1 = gm[1], q2 = gm[2], q3 = gm[3];
          float w0 = __fsub_rn(__fmul_rn(q0.x, __fsub_rn(py, q0.w)),
                               __fmul_rn(q0.y, __fsub_rn(px, q0.z)));
          float w1 = __fsub_rn(__fmul_rn(q1.x, __fsub_rn(py, q1.w)),
                               __fmul_rn(q1.y, __fsub_rn(px, q1.z)));
          float w2 = __fsub_rn(__fmul_rn(q2.x, __fsub_rn(py, q2.w)),
                               __fmul_rn(q2.y, __fsub_rn(px, q2.z)));
          float b0 = __fmul_rn(w0, q3.w);
          float b1 = __fmul_rn(w1, q3.w);
          float b2 = __fmul_rn(w2, q3.w);
          if (b0 >= 0.0f && b1 >= 0.0f && b2 >= 0.0f) {
            float invz = __fadd_rn(__fadd_rn(b0 / q3.x, b1 / q3.y), b2 / q3.z);
            if (invz > EPSF) {
              float zp = 1.0f / invz;
              unsigned long long key =
                  ((unsigned long long)__float_as_uint(zp) << 32) | (unsigned)oiB[fi];
              if (key < bestKey) bestKey = key;
            }
          }
        }
      }
    }
  }

  // exact per-wave per-pixel merge (slots), publish, then block-wide merge
  unsigned long long o = shfl_xor_u64(bestKey, 1);
  if (o < bestKey) bestKey = o;
  o = shfl_xor_u64(bestKey, 2);
  if (o < bestKey) bestKey = o;
  if (slot == 0) fin[w][p] = bestKey;
  __syncthreads();

  int t = threadIdx.x;
  if (t < 16) {
    unsigned long long key = fin[0][t];
    #pragma unroll
    for (int hw_ = 1; hw_ < NWAVE; ++hw_) {
      unsigned long long kk = fin[hw_][t]; if (kk < key) key = kk;
    }
    int xx = wx + (t & 3), yy = wy + (t >> 2);
    float pxx = (float)xx + 0.5f, pyy = (float)yy + 0.5f;
    float o0, o1, o2;
    if (key != KEY_INIT) {
      int best = (int)(unsigned)(key & 0xFFFFFFFFu);
      float zmin = __uint_as_float((unsigned)(key >> 32));
      int pos = inv[b * NF + best];
      const float4* g = &gmB[(size_t)pos * 4];
      float4 q0 = g[0], q1 = g[1], q2 = g[2], q3 = g[3];
      float w0 = __fsub_rn(__fmul_rn(q0.x, __fsub_rn(pyy, q0.w)),
                           __fmul_rn(q0.y, __fsub_rn(pxx, q0.z)));
      float w1 = __fsub_rn(__fmul_rn(q1.x, __fsub_rn(pyy, q1.w)),
                           __fmul_rn(q1.y, __fsub_rn(pxx, q1.z)));
      float w2 = __fsub_rn(__fmul_rn(q2.x, __fsub_rn(pyy, q2.w)),
                           __fmul_rn(q2.y, __fsub_rn(pxx, q2.z)));
      float b0 = __fmul_rn(w0, q3.w), b1 = __fmul_rn(w1, q3.w), b2 = __fmul_rn(w2, q3.w);
      float pc0 = b0 / q3.x, pc1 = b1 / q3.y, pc2 = b2 / q3.z;
      int i0 = f[best * 3 + 0], i1 = f[best * 3 + 1], i2 = f[best * 3 + 2];
      const float* c0p = vc + (size_t)i0 * 3;
      const float* c1p = vc + (size_t)i1 * 3;
      const float* c2p = vc + (size_t)i2 * 3;
      o0 = __fmul_rn(__fadd_rn(__fadd_rn(__fmul_rn(pc0, c0p[0]), __fmul_rn(pc1, c1p[0])),
                               __fmul_rn(pc2, c2p[0])), zmin);
      o1 = __fmul_rn(__fadd_rn(__fadd_rn(__fmul_rn(pc0, c0p[1]), __fmul_rn(pc1, c1p[1])),
                               __fmul_rn(pc2, c2p[1])), zmin);
      o2 = __fmul_rn(__fadd_rn(__fadd_rn(__fmul_rn(pc0, c0p[2]), __fmul_rn(pc1, c1p[2])),
                               __fmul_rn(pc2, c2p[2])), zmin);
    } else {
      o0 = bg[0]; o1 = bg[1]; o2 = bg[2];
    }
    size_t oo = ((size_t)(b * H_IMG + yy) * W_IMG + xx) * 3;
    out[oo + 0] = o0;
    out[oo + 1] = o1;
    out[oo + 2] = o2;
  }
}

extern "C" void kernel_launch(void* const* d_in, const int* in_sizes, int n_in,
                              void* d_out, int out_size, void* d_ws, size_t ws_size,
                              hipStream_t stream) {
  const float* v   = (const float*)d_in[0];
  const float* vc  = (const float*)d_in[1];
  const float* bg  = (const float*)d_in[2];
  const float* cf  = (const float*)d_in[3];
  const float* cc  = (const float*)d_in[4];
  const float* ct  = (const float*)d_in[5];
  const float* crt = (const float*)d_in[6];
  const int*   f   = (const int*)d_in[7];
  float* out = (float*)d_out;
  char* ws = (char*)d_ws;

  float*    zbU   = (float*)(ws + OFF_ZBU);
  float*    zbS   = (float*)(ws + OFF_ZBS);
  float4*   bbS   = (float4*)(ws + OFF_BBS);
  float4*   gmS   = (float4*)(ws + OFF_GMS);
  int*      oiS   = (int*)(ws + OFF_OIS);
  int*      inv   = (int*)(ws + OFF_INV);
  unsigned* chdr  = (unsigned*)(ws + OFF_CHDR);
  unsigned* cnt   = (unsigned*)(ws + OFF_CNT);
  unsigned* offs  = (unsigned*)(ws + OFF_OFFS);

  hipMemsetAsync(cnt, 0, (size_t)NB * NBUCK * 4, stream);
  hipLaunchKernelGGL(zb_init_kernel, dim3((NB * FPAD + 255) / 256), dim3(256), 0, stream,
                     v, f, cf, cc, ct, crt, zbU, cnt, zbS, bbS);
  hipLaunchKernelGGL(scan_kernel, dim3(NB), dim3(1024), 0, stream, cnt, offs, chdr);
  hipLaunchKernelGGL(scatter_kernel, dim3((NB * NF + 255) / 256), dim3(256), 0, stream,
                     v, f, cf, cc, ct, crt, zbU, offs, zbS, bbS, gmS, oiS, inv);
  hipLaunchKernelGGL(raster_kernel, dim3(W_IMG / 4, H_IMG / 4, NB),
                     dim3(256), 0, stream,
                     chdr, zbS, bbS, gmS, oiS, inv, f, vc, bg, out);
}